// Round 2
// baseline (1383.378 us; speedup 1.0000x reference)
//
#include <hip/hip_runtime.h>
#include <stdint.h>

#define T_TOK 8192
#define DD 1024
#define FF 4096
#define EE 16
#define MAX_SLOTS 20480 // sum of per-expert counts padded to 256 <= 16384+16*255
#define MT1 80          // max 256-row m-tiles
#define MT2 160         // max 128-row m-tiles

typedef __attribute__((ext_vector_type(4))) float f32x4;
typedef __attribute__((ext_vector_type(8))) short bf16x8;

__device__ __forceinline__ unsigned short f2bf(float f) {
  union { float f; unsigned u; } v; v.f = f;
  unsigned r = v.u + 0x7FFFu + ((v.u >> 16) & 1u);
  return (unsigned short)(r >> 16);
}

__device__ __forceinline__ void gload16(const void* g, void* l) {
  __builtin_amdgcn_global_load_lds(
      (const __attribute__((address_space(1))) unsigned int*)g,
      (__attribute__((address_space(3))) unsigned int*)l, 16, 0, 0);
}

// ---------------- router ------------------------------------------------------
__global__ void router_kernel(const float* __restrict__ x, const float* __restrict__ Wr,
                              const float* __restrict__ br,
                              int* __restrict__ counts, int* __restrict__ tok_e,
                              int* __restrict__ tok_s, float* __restrict__ tok_w,
                              int* __restrict__ elist) {
  int t = blockIdx.x * blockDim.x + threadIdx.x;
  if (t >= T_TOK) return;
  float acc[EE];
#pragma unroll
  for (int e = 0; e < EE; ++e) acc[e] = br[e];
  const f32x4* x4 = (const f32x4*)(x + (size_t)t * DD);
  for (int d4 = 0; d4 < DD / 4; ++d4) {
    f32x4 xv = x4[d4];
    const float* wr = Wr + (size_t)d4 * 4 * EE;
#pragma unroll
    for (int dd = 0; dd < 4; ++dd)
#pragma unroll
      for (int e = 0; e < EE; ++e) acc[e] += xv[dd] * wr[dd * EE + e];
  }
  int i0 = 0; float v0 = acc[0];
#pragma unroll
  for (int e = 1; e < EE; ++e) if (acc[e] > v0) { v0 = acc[e]; i0 = e; }
  int i1 = -1; float v1 = -3.4e38f;
#pragma unroll
  for (int e = 0; e < EE; ++e) if (e != i0 && acc[e] > v1) { v1 = acc[e]; i1 = e; }
  float p1 = __expf(v1 - v0);
  float w0 = 1.f / (1.f + p1);
  float w1 = p1 * w0;
  int s0 = atomicAdd(&counts[i0], 1);
  int s1 = atomicAdd(&counts[i1], 1);
  tok_e[2 * t] = i0; tok_s[2 * t] = s0; tok_w[2 * t] = w0;
  tok_e[2 * t + 1] = i1; tok_s[2 * t + 1] = s1; tok_w[2 * t + 1] = w1;
  elist[(size_t)i0 * T_TOK + s0] = t;
  elist[(size_t)i1 * T_TOK + s1] = t;
}

// ---------------- scan --------------------------------------------------------
__global__ void scan_kernel(const int* __restrict__ counts, int* __restrict__ off,
                            int* __restrict__ mtb, int* __restrict__ mtb2) {
  if (threadIdx.x == 0 && blockIdx.x == 0) {
    int o = 0, m = 0;
    for (int e = 0; e < EE; ++e) {
      off[e] = o; mtb[e] = m;
      int c = counts[e];
      int mt = (c + 255) / 256;
      o += mt * 256; m += mt;
    }
    off[EE] = o; mtb[EE] = m;
    for (int e = 0; e <= EE; ++e) mtb2[e] = off[e] >> 7;
  }
}

// ---------------- gather ------------------------------------------------------
__global__ void gather_kernel(const float* __restrict__ x, const int* __restrict__ counts,
                              const int* __restrict__ off, const int* __restrict__ elist,
                              unsigned short* __restrict__ Xg) {
  int slot = blockIdx.x;
  if (slot >= off[EE]) return;
  int e = 0;
  while (e < EE - 1 && off[e + 1] <= slot) ++e;
  int s = slot - off[e];
  int tid = threadIdx.x;
  ushort4* dst = (ushort4*)(Xg + (size_t)slot * DD);
  if (s < counts[e]) {
    int t = elist[(size_t)e * T_TOK + s];
    f32x4 v = ((const f32x4*)(x + (size_t)t * DD))[tid];
    ushort4 o;
    o.x = f2bf(v[0]); o.y = f2bf(v[1]); o.z = f2bf(v[2]); o.w = f2bf(v[3]);
    dst[tid] = o;
  } else {
    ushort4 z; z.x = z.y = z.z = z.w = 0;
    dst[tid] = z;
  }
}

// ---------------- transpose+convert fp32[R][C] -> bf16 with optional W13 remap -
__global__ void transpose_conv(const float* __restrict__ src0, unsigned short* __restrict__ dst0,
                               int R, int C, size_t dstEstride, int mode) {
  __shared__ float tile[64][65];
  int e = blockIdx.z;
  const float* src = src0 + (size_t)e * R * C;
  unsigned short* dst = dst0 + (size_t)e * dstEstride;
  int r0 = blockIdx.y * 64, c0 = blockIdx.x * 64;
  int tx = threadIdx.x & 15, ty = threadIdx.x >> 4;
#pragma unroll
  for (int i = 0; i < 4; ++i) {
    int r = i * 16 + ty;
    f32x4 v = *(const f32x4*)(src + (size_t)(r0 + r) * C + c0 + tx * 4);
    tile[r][tx * 4 + 0] = v[0]; tile[r][tx * 4 + 1] = v[1];
    tile[r][tx * 4 + 2] = v[2]; tile[r][tx * 4 + 3] = v[3];
  }
  __syncthreads();
#pragma unroll
  for (int i = 0; i < 4; ++i) {
    int c = i * 16 + ty;
    int cg = c0 + c;
    int rp = (mode == 0) ? cg : ((cg >> 7) * 256 + (cg & 127) + ((mode == 2) ? 128 : 0));
    ushort4 o;
    o.x = f2bf(tile[tx * 4 + 0][c]); o.y = f2bf(tile[tx * 4 + 1][c]);
    o.z = f2bf(tile[tx * 4 + 2][c]); o.w = f2bf(tile[tx * 4 + 3][c]);
    *(ushort4*)(dst + (size_t)rp * R + r0 + tx * 4) = o;
  }
}

// ---------------- GEMM1: 256x256 tile, BK=64, 8 waves, counted-vmcnt phases ----
// B = W13t interleaved: tile cols [0,128) = W1 (silu input), [128,256) = W3 (gate).
#define PHASE(MQ, NQ, READA)                                                        \
  do {                                                                              \
    if (READA) {                                                                    \
      _Pragma("unroll") for (int mi = 0; mi < 4; ++mi) {                            \
        int r = wr * 128 + MQ * 64 + mi * 16 + fr;                                  \
        pa[mi][0] = *(const bf16x8*)(lds + curOff + (r << 7) + ((fkk << 1) ^ swz)); \
        pa[mi][1] = *(const bf16x8*)(lds + curOff + (r << 7) + ((64 + (fkk << 1)) ^ swz)); \
      }                                                                             \
    }                                                                               \
    _Pragma("unroll") for (int ni = 0; ni < 2; ++ni) {                              \
      int r = wc * 64 + NQ * 32 + ni * 16 + fr;                                     \
      pb[ni][0] = *(const bf16x8*)(lds + curOff + 32768 + (r << 7) + ((fkk << 1) ^ swz)); \
      pb[ni][1] = *(const bf16x8*)(lds + curOff + 32768 + (r << 7) + ((64 + (fkk << 1)) ^ swz)); \
    }                                                                               \
    __builtin_amdgcn_s_barrier();                                                   \
    asm volatile("s_waitcnt lgkmcnt(0)" ::: "memory");                              \
    __builtin_amdgcn_sched_barrier(0);                                              \
    __builtin_amdgcn_s_setprio(1);                                                  \
    _Pragma("unroll") for (int mi = 0; mi < 4; ++mi)                                \
      _Pragma("unroll") for (int ni = 0; ni < 2; ++ni) {                            \
        acc[MQ * 4 + mi][NQ * 2 + ni] = __builtin_amdgcn_mfma_f32_16x16x32_bf16(    \
            pa[mi][0], pb[ni][0], acc[MQ * 4 + mi][NQ * 2 + ni], 0, 0, 0);          \
        acc[MQ * 4 + mi][NQ * 2 + ni] = __builtin_amdgcn_mfma_f32_16x16x32_bf16(    \
            pa[mi][1], pb[ni][1], acc[MQ * 4 + mi][NQ * 2 + ni], 0, 0, 0);          \
      }                                                                             \
    __builtin_amdgcn_s_setprio(0);                                                  \
    __builtin_amdgcn_s_barrier();                                                   \
  } while (0)

__global__ __launch_bounds__(512, 2) void gemm1_kernel(
    const unsigned short* __restrict__ Xg, const unsigned short* __restrict__ W13t,
    const int* __restrict__ off, const int* __restrict__ mtb,
    unsigned short* __restrict__ H) {
  __shared__ __align__(16) char lds[131072];
  int ty = blockIdx.y;
  if (ty >= mtb[EE]) return;
  int e = 0;
  while (e < EE - 1 && mtb[e + 1] <= ty) ++e;
  int m0 = off[e] + (ty - mtb[e]) * 256;
  int n0s = blockIdx.x * 256;
  int hcol0 = blockIdx.x * 128;
  const unsigned short* A = Xg + (size_t)m0 * DD;
  const unsigned short* B = W13t + ((size_t)e * (2 * FF) + n0s) * DD;

  int tid = threadIdx.x, lane = tid & 63, wid = tid >> 6;
  int wr = wid >> 2, wc = wid & 3;
  int fr = lane & 15, fkk = (lane >> 4) * 8;
  int swz = (fr & 7) << 4;
  int xc = ((tid & 7) ^ ((tid >> 3) & 7)) << 3;  // pre-swizzled global elem offset

  auto stage = [&](int bufOff, int k0) {
#pragma unroll
    for (int j = 0; j < 4; ++j) {
      int row = j * 64 + (tid >> 3);
      gload16(A + (size_t)row * DD + k0 + xc, lds + bufOff + j * 8192 + tid * 16);
      gload16(B + (size_t)row * DD + k0 + xc, lds + bufOff + 32768 + j * 8192 + tid * 16);
    }
  };

  f32x4 acc[8][4] = {};
  bf16x8 pa[4][2], pb[2][2];

  asm volatile("s_waitcnt vmcnt(0)" ::: "memory");
  stage(0, 0);
  stage(65536, 64);
  asm volatile("s_waitcnt vmcnt(8)" ::: "memory");
  __builtin_amdgcn_s_barrier();

  for (int kt = 0; kt < 16; ++kt) {
    int curOff = (kt & 1) << 16;
    PHASE(0, 0, 1);
    PHASE(0, 1, 0);
    PHASE(1, 0, 1);
    PHASE(1, 1, 0);
    if (kt < 14) {
      stage(curOff, (kt + 2) * 64);  // buf just freed by this iteration's reads
      asm volatile("s_waitcnt vmcnt(8)" ::: "memory");
      __builtin_amdgcn_s_barrier();
    } else if (kt == 14) {
      asm volatile("s_waitcnt vmcnt(0)" ::: "memory");
      __builtin_amdgcn_s_barrier();
    }
  }

  // epilogue: SwiGLU combine via LDS, then coalesced bf16 store
  float* L3 = (float*)lds;                               // [128][132] f32
  unsigned short* HO = (unsigned short*)(lds + 69632);   // [128][128] bf16
  int frow = (lane >> 4) * 4;
#pragma unroll 1
  for (int h = 0; h < 2; ++h) {
    __syncthreads();
    if (wr == h && wc >= 2) {
#pragma unroll
      for (int mi = 0; mi < 8; ++mi)
#pragma unroll
        for (int ni = 0; ni < 4; ++ni)
#pragma unroll
          for (int i = 0; i < 4; ++i)
            L3[(mi * 16 + frow + i) * 132 + (wc - 2) * 64 + ni * 16 + fr] = acc[mi][ni][i];
    }
    __syncthreads();
    if (wr == h && wc < 2) {
#pragma unroll
      for (int mi = 0; mi < 8; ++mi)
#pragma unroll
        for (int ni = 0; ni < 4; ++ni)
#pragma unroll
          for (int i = 0; i < 4; ++i) {
            float c1 = acc[mi][ni][i];
            float c3 = L3[(mi * 16 + frow + i) * 132 + wc * 64 + ni * 16 + fr];
            float hv = c1 / (1.f + __expf(-c1)) * c3;
            HO[(mi * 16 + frow + i) * 128 + wc * 64 + ni * 16 + fr] = f2bf(hv);
          }
    }
    __syncthreads();
#pragma unroll
    for (int s = 0; s < 4; ++s) {
      int flat = s * 8192 + tid * 16;
      int rr = flat >> 8, cb2 = flat & 255;
      *(bf16x8*)(H + (size_t)(m0 + h * 128 + rr) * FF + hcol0 + (cb2 >> 1)) =
          *(const bf16x8*)((const char*)HO + flat);
    }
    __syncthreads();
  }
}

// ---------------- GEMM2: Y = H @ W2t (128x128, unchanged structure) ------------
__global__ __launch_bounds__(256, 2) void gemm2_kernel(
    const unsigned short* __restrict__ H, const unsigned short* __restrict__ W2t,
    const int* __restrict__ off, const int* __restrict__ mtb2, float* __restrict__ Y) {
  __shared__ __align__(16) unsigned short As[128][32];
  __shared__ __align__(16) unsigned short Bs[128][32];
  int ty = blockIdx.y;
  if (ty >= mtb2[EE]) return;
  int e = 0;
  while (e < EE - 1 && mtb2[e + 1] <= ty) ++e;
  int m0 = off[e] + (ty - mtb2[e]) * 128;
  int n0 = blockIdx.x * 128;
  const unsigned short* A = H + (size_t)m0 * FF;
  const unsigned short* B = W2t + ((size_t)e * DD + n0) * FF;
  int tid = threadIdx.x, lane = tid & 63, wid = tid >> 6;
  int wm = wid >> 1, wn = wid & 1;
  f32x4 acc[4][4] = {};
  int fr = lane & 15, fk = (lane >> 4) * 8;
  for (int k0 = 0; k0 < FF; k0 += 32) {
#pragma unroll
    for (int r = 0; r < 2; ++r) {
      int c = r * 256 + tid;
      int row = c >> 2, ch = c & 3;
      gload16(A + (size_t)row * FF + k0 + ch * 8, (char*)As + c * 16);
      gload16(B + (size_t)row * FF + k0 + ch * 8, (char*)Bs + c * 16);
    }
    __syncthreads();
    bf16x8 a[4], b[4];
#pragma unroll
    for (int mi = 0; mi < 4; ++mi) a[mi] = *(const bf16x8*)&As[wm * 64 + mi * 16 + fr][fk];
#pragma unroll
    for (int ni = 0; ni < 4; ++ni) b[ni] = *(const bf16x8*)&Bs[wn * 64 + ni * 16 + fr][fk];
#pragma unroll
    for (int mi = 0; mi < 4; ++mi)
#pragma unroll
      for (int ni = 0; ni < 4; ++ni)
        acc[mi][ni] = __builtin_amdgcn_mfma_f32_16x16x32_bf16(a[mi], b[ni], acc[mi][ni], 0, 0, 0);
    __syncthreads();
  }
#pragma unroll
  for (int mi = 0; mi < 4; ++mi)
#pragma unroll
    for (int ni = 0; ni < 4; ++ni)
#pragma unroll
      for (int i = 0; i < 4; ++i) {
        int row = m0 + wm * 64 + mi * 16 + (lane >> 4) * 4 + i;
        int col = n0 + wn * 64 + ni * 16 + (lane & 15);
        Y[(size_t)row * DD + col] = acc[mi][ni][i];
      }
}

// ---------------- LayerNorm + weighted combine ---------------------------------
__global__ void ln_combine_kernel(const float* __restrict__ Y, const int* __restrict__ tok_e,
                                  const int* __restrict__ tok_s, const float* __restrict__ tok_w,
                                  const int* __restrict__ off, const float* __restrict__ gamma,
                                  const float* __restrict__ beta, float* __restrict__ out) {
  int t = blockIdx.x, tid = threadIdx.x;
  __shared__ float red[8];
  f32x4 o = {0.f, 0.f, 0.f, 0.f};
  for (int k = 0; k < 2; ++k) {
    int e = tok_e[2 * t + k], s = tok_s[2 * t + k];
    float w = tok_w[2 * t + k];
    int slot = off[e] + s;
    f32x4 v = ((const f32x4*)(Y + (size_t)slot * DD))[tid];
    float sum = v[0] + v[1] + v[2] + v[3];
    float sq = v[0] * v[0] + v[1] * v[1] + v[2] * v[2] + v[3] * v[3];
    for (int d = 32; d > 0; d >>= 1) {
      sum += __shfl_down(sum, d);
      sq += __shfl_down(sq, d);
    }
    int wv = tid >> 6, lane = tid & 63;
    if (lane == 0) { red[wv * 2] = sum; red[wv * 2 + 1] = sq; }
    __syncthreads();
    float S1 = red[0] + red[2] + red[4] + red[6];
    float S2 = red[1] + red[3] + red[5] + red[7];
    __syncthreads();
    float mu = S1 * (1.f / (float)DD);
    float var = S2 * (1.f / (float)DD) - mu * mu;
    float rs = rsqrtf(var + 1e-5f);
    f32x4 g = ((const f32x4*)(gamma + (size_t)e * DD))[tid];
    f32x4 b = ((const f32x4*)(beta + (size_t)e * DD))[tid];
#pragma unroll
    for (int j = 0; j < 4; ++j) o[j] += w * ((v[j] - mu) * rs * g[j] + b[j]);
  }
  ((f32x4*)out)[(size_t)t * (DD / 4) + tid] = o;
}

// ---------------- launch -------------------------------------------------------
extern "C" void kernel_launch(void* const* d_in, const int* in_sizes, int n_in,
                              void* d_out, int out_size, void* d_ws, size_t ws_size,
                              hipStream_t stream) {
  const float* x = (const float*)d_in[0];
  const float* Wr = (const float*)d_in[1];
  const float* br = (const float*)d_in[2];
  const float* W1 = (const float*)d_in[3];
  const float* W3 = (const float*)d_in[4];
  const float* W2 = (const float*)d_in[5];
  const float* gamma = (const float*)d_in[6];
  const float* beta = (const float*)d_in[7];
  float* out = (float*)d_out;

  char* w = (char*)d_ws;
  size_t o = 0;
  auto alloc = [&](size_t bytes) {
    void* p = w + o;
    o += (bytes + 255) & ~(size_t)255;
    return p;
  };
  int* counts = (int*)alloc(EE * 4);
  int* off = (int*)alloc((EE + 1) * 4);
  int* mtb = (int*)alloc((EE + 1) * 4);
  int* mtb2 = (int*)alloc((EE + 1) * 4);
  int* tok_e = (int*)alloc(2 * T_TOK * 4);
  int* tok_s = (int*)alloc(2 * T_TOK * 4);
  float* tok_w = (float*)alloc(2 * T_TOK * 4);
  int* elist = (int*)alloc((size_t)EE * T_TOK * 4);
  unsigned short* Xg = (unsigned short*)alloc((size_t)MAX_SLOTS * DD * 2);
  unsigned short* W13t = (unsigned short*)alloc((size_t)EE * 2 * FF * DD * 2);
  unsigned short* W2t = (unsigned short*)alloc((size_t)EE * DD * FF * 2);
  unsigned short* Hb = (unsigned short*)alloc((size_t)MAX_SLOTS * FF * 2);
  float* Y = (float*)alloc((size_t)MAX_SLOTS * DD * 4);

  hipMemsetAsync(counts, 0, EE * sizeof(int), stream);
  router_kernel<<<T_TOK / 256, 256, 0, stream>>>(x, Wr, br, counts, tok_e, tok_s, tok_w, elist);
  scan_kernel<<<1, 64, 0, stream>>>(counts, off, mtb, mtb2);
  gather_kernel<<<MAX_SLOTS, 256, 0, stream>>>(x, counts, off, elist, Xg);
  transpose_conv<<<dim3(FF / 64, DD / 64, EE), 256, 0, stream>>>(W1, W13t, DD, FF, (size_t)2 * FF * DD, 1);
  transpose_conv<<<dim3(FF / 64, DD / 64, EE), 256, 0, stream>>>(W3, W13t, DD, FF, (size_t)2 * FF * DD, 2);
  transpose_conv<<<dim3(DD / 64, FF / 64, EE), 256, 0, stream>>>(W2, W2t, FF, DD, (size_t)FF * DD, 0);
  gemm1_kernel<<<dim3(2 * FF / 256, MT1), 512, 0, stream>>>(Xg, W13t, off, mtb, Hb);
  gemm2_kernel<<<dim3(DD / 128, MT2), 256, 0, stream>>>(Hb, W2t, off, mtb2, Y);
  ln_combine_kernel<<<T_TOK, 256, 0, stream>>>(Y, tok_e, tok_s, tok_w, off, gamma, beta, out);
}

// Round 3
// 1325.834 us; speedup vs baseline: 1.0434x; 1.0434x over previous
//
#include <hip/hip_runtime.h>
#include <stdint.h>

#define T_TOK 8192
#define DD 1024
#define FF 4096
#define EE 16
#define MAX_SLOTS 20480 // sum of per-expert counts padded to 256 <= 16384+16*255
#define MT1 80          // max 256-row m-tiles
#define MT2 160         // max 128-row m-tiles

typedef __attribute__((ext_vector_type(4))) float f32x4;
typedef __attribute__((ext_vector_type(8))) short bf16x8;

__device__ __forceinline__ unsigned short f2bf(float f) {
  union { float f; unsigned u; } v; v.f = f;
  unsigned r = v.u + 0x7FFFu + ((v.u >> 16) & 1u);
  return (unsigned short)(r >> 16);
}

__device__ __forceinline__ void gload16(const void* g, void* l) {
  __builtin_amdgcn_global_load_lds(
      (const __attribute__((address_space(1))) unsigned int*)g,
      (__attribute__((address_space(3))) unsigned int*)l, 16, 0, 0);
}

// ---------------- router ------------------------------------------------------
__global__ void router_kernel(const float* __restrict__ x, const float* __restrict__ Wr,
                              const float* __restrict__ br,
                              int* __restrict__ counts, int* __restrict__ tok_e,
                              int* __restrict__ tok_s, float* __restrict__ tok_w,
                              int* __restrict__ elist) {
  int t = blockIdx.x * blockDim.x + threadIdx.x;
  if (t >= T_TOK) return;
  float acc[EE];
#pragma unroll
  for (int e = 0; e < EE; ++e) acc[e] = br[e];
  const f32x4* x4 = (const f32x4*)(x + (size_t)t * DD);
  for (int d4 = 0; d4 < DD / 4; ++d4) {
    f32x4 xv = x4[d4];
    const float* wr = Wr + (size_t)d4 * 4 * EE;
#pragma unroll
    for (int dd = 0; dd < 4; ++dd)
#pragma unroll
      for (int e = 0; e < EE; ++e) acc[e] += xv[dd] * wr[dd * EE + e];
  }
  int i0 = 0; float v0 = acc[0];
#pragma unroll
  for (int e = 1; e < EE; ++e) if (acc[e] > v0) { v0 = acc[e]; i0 = e; }
  int i1 = -1; float v1 = -3.4e38f;
#pragma unroll
  for (int e = 0; e < EE; ++e) if (e != i0 && acc[e] > v1) { v1 = acc[e]; i1 = e; }
  float p1 = __expf(v1 - v0);
  float w0 = 1.f / (1.f + p1);
  float w1 = p1 * w0;
  int s0 = atomicAdd(&counts[i0], 1);
  int s1 = atomicAdd(&counts[i1], 1);
  tok_e[2 * t] = i0; tok_s[2 * t] = s0; tok_w[2 * t] = w0;
  tok_e[2 * t + 1] = i1; tok_s[2 * t + 1] = s1; tok_w[2 * t + 1] = w1;
  elist[(size_t)i0 * T_TOK + s0] = t;
  elist[(size_t)i1 * T_TOK + s1] = t;
}

// ---------------- scan --------------------------------------------------------
__global__ void scan_kernel(const int* __restrict__ counts, int* __restrict__ off,
                            int* __restrict__ mtb, int* __restrict__ mtb2) {
  if (threadIdx.x == 0 && blockIdx.x == 0) {
    int o = 0, m = 0;
    for (int e = 0; e < EE; ++e) {
      off[e] = o; mtb[e] = m;
      int c = counts[e];
      int mt = (c + 255) / 256;
      o += mt * 256; m += mt;
    }
    off[EE] = o; mtb[EE] = m;
    for (int e = 0; e <= EE; ++e) mtb2[e] = off[e] >> 7;
  }
}

// ---------------- gather ------------------------------------------------------
__global__ void gather_kernel(const float* __restrict__ x, const int* __restrict__ counts,
                              const int* __restrict__ off, const int* __restrict__ elist,
                              unsigned short* __restrict__ Xg) {
  int slot = blockIdx.x;
  if (slot >= off[EE]) return;
  int e = 0;
  while (e < EE - 1 && off[e + 1] <= slot) ++e;
  int s = slot - off[e];
  int tid = threadIdx.x;
  ushort4* dst = (ushort4*)(Xg + (size_t)slot * DD);
  if (s < counts[e]) {
    int t = elist[(size_t)e * T_TOK + s];
    f32x4 v = ((const f32x4*)(x + (size_t)t * DD))[tid];
    ushort4 o;
    o.x = f2bf(v[0]); o.y = f2bf(v[1]); o.z = f2bf(v[2]); o.w = f2bf(v[3]);
    dst[tid] = o;
  } else {
    ushort4 z; z.x = z.y = z.z = z.w = 0;
    dst[tid] = z;
  }
}

// ---------------- transpose+convert fp32[R][C] -> bf16 with optional W13 remap -
__global__ void transpose_conv(const float* __restrict__ src0, unsigned short* __restrict__ dst0,
                               int R, int C, size_t dstEstride, int mode) {
  __shared__ float tile[64][65];
  int e = blockIdx.z;
  const float* src = src0 + (size_t)e * R * C;
  unsigned short* dst = dst0 + (size_t)e * dstEstride;
  int r0 = blockIdx.y * 64, c0 = blockIdx.x * 64;
  int tx = threadIdx.x & 15, ty = threadIdx.x >> 4;
#pragma unroll
  for (int i = 0; i < 4; ++i) {
    int r = i * 16 + ty;
    f32x4 v = *(const f32x4*)(src + (size_t)(r0 + r) * C + c0 + tx * 4);
    tile[r][tx * 4 + 0] = v[0]; tile[r][tx * 4 + 1] = v[1];
    tile[r][tx * 4 + 2] = v[2]; tile[r][tx * 4 + 3] = v[3];
  }
  __syncthreads();
#pragma unroll
  for (int i = 0; i < 4; ++i) {
    int c = i * 16 + ty;
    int cg = c0 + c;
    int rp = (mode == 0) ? cg : ((cg >> 7) * 256 + (cg & 127) + ((mode == 2) ? 128 : 0));
    ushort4 o;
    o.x = f2bf(tile[tx * 4 + 0][c]); o.y = f2bf(tile[tx * 4 + 1][c]);
    o.z = f2bf(tile[tx * 4 + 2][c]); o.w = f2bf(tile[tx * 4 + 3][c]);
    *(ushort4*)(dst + (size_t)rp * R + r0 + tx * 4) = o;
  }
}

// ---------------- GEMM1: 256x256 tile, BK=64, 8 waves, fine-interleaved phases -
// LDS per K-tile buffer (64KB): A at +0, B at +32768; each as [kh][256 rows][64B].
// Row swizzle: LDS[row][slot s] holds G[row][kh*32 + (s ^ ((row>>1)&3))*8].
// Phase (kh, MQ): 16 independent MFMAs; stages 2 loads of K-tile kt+1;
// vmcnt(4) at phases 1 and 3 only (forces 4-oldest granules; never drains).
#define PHASE(KH, MQ, STG, VMW)                                                     \
  do {                                                                              \
    if (MQ == 0) {                                                                  \
      _Pragma("unroll") for (int ni = 0; ni < 4; ++ni)                              \
        pb[ni] = *(const bf16x8*)(lds + cb + 32768 + KH * 16384 +                   \
                                  (wc * 64 + ni * 16 + fr) * 64 + (fkb ^ swz));     \
    }                                                                               \
    _Pragma("unroll") for (int mi = 0; mi < 4; ++mi)                                \
      pa[mi] = *(const bf16x8*)(lds + cb + KH * 16384 +                             \
                                (wr * 128 + MQ * 64 + mi * 16 + fr) * 64 + (fkb ^ swz)); \
    STG;                                                                            \
    VMW;                                                                            \
    __builtin_amdgcn_s_barrier();                                                   \
    asm volatile("s_waitcnt lgkmcnt(0)" ::: "memory");                              \
    __builtin_amdgcn_sched_barrier(0);                                              \
    __builtin_amdgcn_s_setprio(1);                                                  \
    _Pragma("unroll") for (int mi = 0; mi < 4; ++mi)                                \
      _Pragma("unroll") for (int ni = 0; ni < 4; ++ni)                              \
        acc[MQ * 4 + mi][ni] = __builtin_amdgcn_mfma_f32_16x16x32_bf16(             \
            pa[mi], pb[ni], acc[MQ * 4 + mi][ni], 0, 0, 0);                         \
    __builtin_amdgcn_s_setprio(0);                                                  \
    __builtin_amdgcn_s_barrier();                                                   \
  } while (0)

__global__ __launch_bounds__(512, 2) void gemm1_kernel(
    const unsigned short* __restrict__ Xg, const unsigned short* __restrict__ W13t,
    const int* __restrict__ off, const int* __restrict__ mtb,
    unsigned short* __restrict__ H) {
  __shared__ __align__(16) char lds[131072];
  int ty = blockIdx.y;
  if (ty >= mtb[EE]) return;
  int e = 0;
  while (e < EE - 1 && mtb[e + 1] <= ty) ++e;
  int m0 = off[e] + (ty - mtb[e]) * 256;
  int n0s = blockIdx.x * 256;
  int hcol0 = blockIdx.x * 128;
  const unsigned short* Ag = Xg + (size_t)m0 * DD;
  const unsigned short* Bg = W13t + ((size_t)e * (2 * FF) + n0s) * DD;

  int tid = threadIdx.x, lane = tid & 63, wid = tid >> 6;
  int wr = wid >> 2, wc = wid & 3;
  int fr = lane & 15, fkb = ((lane >> 4) * 8) * 2;  // k-byte within 64B row
  int swz = ((fr >> 1) & 3) << 4;
  int ce8 = ((tid & 3) ^ ((tid >> 3) & 3)) * 8;  // inverse-swizzled source chunk

  auto stage2A = [&](int dst, int kk, int kh) {
#pragma unroll
    for (int L = 0; L < 2; ++L) {
      int row = L * 128 + (tid >> 2);
      gload16(Ag + (size_t)row * DD + kk + kh * 32 + ce8,
              lds + dst + kh * 16384 + L * 8192 + tid * 16);
    }
  };
  auto stage2B = [&](int dst, int kk, int kh) {
#pragma unroll
    for (int L = 0; L < 2; ++L) {
      int row = L * 128 + (tid >> 2);
      gload16(Bg + (size_t)row * DD + kk + kh * 32 + ce8,
              lds + dst + 32768 + kh * 16384 + L * 8192 + tid * 16);
    }
  };

  f32x4 acc[8][4] = {};
  bf16x8 pa[4], pb[4];

  // prologue: stage K-tile 0, force its kh0 granules, barrier
  asm volatile("s_waitcnt vmcnt(0)" ::: "memory");
  stage2A(0, 0, 0); stage2B(0, 0, 0); stage2A(0, 0, 1); stage2B(0, 0, 1);
  asm volatile("s_waitcnt vmcnt(4)" ::: "memory");
  __builtin_amdgcn_s_barrier();

  for (int kt = 0; kt < 16; ++kt) {
    int cb = (kt & 1) << 16;
    int nb = ((kt + 1) & 1) << 16;
    int kn = (kt + 1) * 64;
    bool st = kt < 15;
    PHASE(0, 0, if (st) stage2A(nb, kn, 0), ((void)0));
    if (st) {
      PHASE(0, 1, stage2B(nb, kn, 0), asm volatile("s_waitcnt vmcnt(4)" ::: "memory"));
      PHASE(1, 0, stage2A(nb, kn, 1), ((void)0));
      PHASE(1, 1, stage2B(nb, kn, 1), asm volatile("s_waitcnt vmcnt(4)" ::: "memory"));
    } else {
      PHASE(0, 1, ((void)0), asm volatile("s_waitcnt vmcnt(0)" ::: "memory"));
      PHASE(1, 0, ((void)0), ((void)0));
      PHASE(1, 1, ((void)0), ((void)0));
    }
  }

  // epilogue: SwiGLU combine via LDS, then coalesced bf16 store
  float* L3 = (float*)lds;                               // [128][132] f32
  unsigned short* HO = (unsigned short*)(lds + 69632);   // [128][128] bf16
  int frow = (lane >> 4) * 4;
#pragma unroll 1
  for (int h = 0; h < 2; ++h) {
    __syncthreads();
    if (wr == h && wc >= 2) {
#pragma unroll
      for (int mi = 0; mi < 8; ++mi)
#pragma unroll
        for (int ni = 0; ni < 4; ++ni)
#pragma unroll
          for (int i = 0; i < 4; ++i)
            L3[(mi * 16 + frow + i) * 132 + (wc - 2) * 64 + ni * 16 + fr] = acc[mi][ni][i];
    }
    __syncthreads();
    if (wr == h && wc < 2) {
#pragma unroll
      for (int mi = 0; mi < 8; ++mi)
#pragma unroll
        for (int ni = 0; ni < 4; ++ni)
#pragma unroll
          for (int i = 0; i < 4; ++i) {
            float c1 = acc[mi][ni][i];
            float c3 = L3[(mi * 16 + frow + i) * 132 + wc * 64 + ni * 16 + fr];
            float hv = c1 / (1.f + __expf(-c1)) * c3;
            HO[(mi * 16 + frow + i) * 128 + wc * 64 + ni * 16 + fr] = f2bf(hv);
          }
    }
    __syncthreads();
#pragma unroll
    for (int s = 0; s < 4; ++s) {
      int flat = s * 8192 + tid * 16;
      int rr = flat >> 8, cb2 = flat & 255;
      *(bf16x8*)(H + (size_t)(m0 + h * 128 + rr) * FF + hcol0 + (cb2 >> 1)) =
          *(const bf16x8*)((const char*)HO + flat);
    }
    __syncthreads();
  }
}

// ---------------- GEMM2: Y = H @ W2t (128x128, unchanged structure) ------------
__global__ __launch_bounds__(256, 2) void gemm2_kernel(
    const unsigned short* __restrict__ H, const unsigned short* __restrict__ W2t,
    const int* __restrict__ off, const int* __restrict__ mtb2, float* __restrict__ Y) {
  __shared__ __align__(16) unsigned short As[128][32];
  __shared__ __align__(16) unsigned short Bs[128][32];
  int ty = blockIdx.y;
  if (ty >= mtb2[EE]) return;
  int e = 0;
  while (e < EE - 1 && mtb2[e + 1] <= ty) ++e;
  int m0 = off[e] + (ty - mtb2[e]) * 128;
  int n0 = blockIdx.x * 128;
  const unsigned short* A = H + (size_t)m0 * FF;
  const unsigned short* B = W2t + ((size_t)e * DD + n0) * FF;
  int tid = threadIdx.x, lane = tid & 63, wid = tid >> 6;
  int wm = wid >> 1, wn = wid & 1;
  f32x4 acc[4][4] = {};
  int fr = lane & 15, fk = (lane >> 4) * 8;
  for (int k0 = 0; k0 < FF; k0 += 32) {
#pragma unroll
    for (int r = 0; r < 2; ++r) {
      int c = r * 256 + tid;
      int row = c >> 2, ch = c & 3;
      gload16(A + (size_t)row * FF + k0 + ch * 8, (char*)As + c * 16);
      gload16(B + (size_t)row * FF + k0 + ch * 8, (char*)Bs + c * 16);
    }
    __syncthreads();
    bf16x8 a[4], b[4];
#pragma unroll
    for (int mi = 0; mi < 4; ++mi) a[mi] = *(const bf16x8*)&As[wm * 64 + mi * 16 + fr][fk];
#pragma unroll
    for (int ni = 0; ni < 4; ++ni) b[ni] = *(const bf16x8*)&Bs[wn * 64 + ni * 16 + fr][fk];
#pragma unroll
    for (int mi = 0; mi < 4; ++mi)
#pragma unroll
      for (int ni = 0; ni < 4; ++ni)
        acc[mi][ni] = __builtin_amdgcn_mfma_f32_16x16x32_bf16(a[mi], b[ni], acc[mi][ni], 0, 0, 0);
    __syncthreads();
  }
#pragma unroll
  for (int mi = 0; mi < 4; ++mi)
#pragma unroll
    for (int ni = 0; ni < 4; ++ni)
#pragma unroll
      for (int i = 0; i < 4; ++i) {
        int row = m0 + wm * 64 + mi * 16 + (lane >> 4) * 4 + i;
        int col = n0 + wn * 64 + ni * 16 + (lane & 15);
        Y[(size_t)row * DD + col] = acc[mi][ni][i];
      }
}

// ---------------- LayerNorm + weighted combine ---------------------------------
__global__ void ln_combine_kernel(const float* __restrict__ Y, const int* __restrict__ tok_e,
                                  const int* __restrict__ tok_s, const float* __restrict__ tok_w,
                                  const int* __restrict__ off, const float* __restrict__ gamma,
                                  const float* __restrict__ beta, float* __restrict__ out) {
  int t = blockIdx.x, tid = threadIdx.x;
  __shared__ float red[8];
  f32x4 o = {0.f, 0.f, 0.f, 0.f};
  for (int k = 0; k < 2; ++k) {
    int e = tok_e[2 * t + k], s = tok_s[2 * t + k];
    float w = tok_w[2 * t + k];
    int slot = off[e] + s;
    f32x4 v = ((const f32x4*)(Y + (size_t)slot * DD))[tid];
    float sum = v[0] + v[1] + v[2] + v[3];
    float sq = v[0] * v[0] + v[1] * v[1] + v[2] * v[2] + v[3] * v[3];
    for (int d = 32; d > 0; d >>= 1) {
      sum += __shfl_down(sum, d);
      sq += __shfl_down(sq, d);
    }
    int wv = tid >> 6, lane = tid & 63;
    if (lane == 0) { red[wv * 2] = sum; red[wv * 2 + 1] = sq; }
    __syncthreads();
    float S1 = red[0] + red[2] + red[4] + red[6];
    float S2 = red[1] + red[3] + red[5] + red[7];
    __syncthreads();
    float mu = S1 * (1.f / (float)DD);
    float var = S2 * (1.f / (float)DD) - mu * mu;
    float rs = rsqrtf(var + 1e-5f);
    f32x4 g = ((const f32x4*)(gamma + (size_t)e * DD))[tid];
    f32x4 b = ((const f32x4*)(beta + (size_t)e * DD))[tid];
#pragma unroll
    for (int j = 0; j < 4; ++j) o[j] += w * ((v[j] - mu) * rs * g[j] + b[j]);
  }
  ((f32x4*)out)[(size_t)t * (DD / 4) + tid] = o;
}

// ---------------- launch -------------------------------------------------------
extern "C" void kernel_launch(void* const* d_in, const int* in_sizes, int n_in,
                              void* d_out, int out_size, void* d_ws, size_t ws_size,
                              hipStream_t stream) {
  const float* x = (const float*)d_in[0];
  const float* Wr = (const float*)d_in[1];
  const float* br = (const float*)d_in[2];
  const float* W1 = (const float*)d_in[3];
  const float* W3 = (const float*)d_in[4];
  const float* W2 = (const float*)d_in[5];
  const float* gamma = (const float*)d_in[6];
  const float* beta = (const float*)d_in[7];
  float* out = (float*)d_out;

  char* w = (char*)d_ws;
  size_t o = 0;
  auto alloc = [&](size_t bytes) {
    void* p = w + o;
    o += (bytes + 255) & ~(size_t)255;
    return p;
  };
  int* counts = (int*)alloc(EE * 4);
  int* off = (int*)alloc((EE + 1) * 4);
  int* mtb = (int*)alloc((EE + 1) * 4);
  int* mtb2 = (int*)alloc((EE + 1) * 4);
  int* tok_e = (int*)alloc(2 * T_TOK * 4);
  int* tok_s = (int*)alloc(2 * T_TOK * 4);
  float* tok_w = (float*)alloc(2 * T_TOK * 4);
  int* elist = (int*)alloc((size_t)EE * T_TOK * 4);
  unsigned short* Xg = (unsigned short*)alloc((size_t)MAX_SLOTS * DD * 2);
  unsigned short* W13t = (unsigned short*)alloc((size_t)EE * 2 * FF * DD * 2);
  unsigned short* W2t = (unsigned short*)alloc((size_t)EE * DD * FF * 2);
  unsigned short* Hb = (unsigned short*)alloc((size_t)MAX_SLOTS * FF * 2);
  float* Y = (float*)alloc((size_t)MAX_SLOTS * DD * 4);

  hipMemsetAsync(counts, 0, EE * sizeof(int), stream);
  router_kernel<<<T_TOK / 256, 256, 0, stream>>>(x, Wr, br, counts, tok_e, tok_s, tok_w, elist);
  scan_kernel<<<1, 64, 0, stream>>>(counts, off, mtb, mtb2);
  gather_kernel<<<MAX_SLOTS, 256, 0, stream>>>(x, counts, off, elist, Xg);
  transpose_conv<<<dim3(FF / 64, DD / 64, EE), 256, 0, stream>>>(W1, W13t, DD, FF, (size_t)2 * FF * DD, 1);
  transpose_conv<<<dim3(FF / 64, DD / 64, EE), 256, 0, stream>>>(W3, W13t, DD, FF, (size_t)2 * FF * DD, 2);
  transpose_conv<<<dim3(DD / 64, FF / 64, EE), 256, 0, stream>>>(W2, W2t, FF, DD, (size_t)FF * DD, 0);
  gemm1_kernel<<<dim3(2 * FF / 256, MT1), 512, 0, stream>>>(Xg, W13t, off, mtb, Hb);
  gemm2_kernel<<<dim3(DD / 128, MT2), 256, 0, stream>>>(Hb, W2t, off, mtb2, Y);
  ln_combine_kernel<<<T_TOK, 256, 0, stream>>>(Y, tok_e, tok_s, tok_w, off, gamma, beta, out);
}

// Round 4
// 1317.183 us; speedup vs baseline: 1.0503x; 1.0066x over previous
//
#include <hip/hip_runtime.h>
#include <stdint.h>

#define T_TOK 8192
#define DD 1024
#define FF 4096
#define EE 16
#define MAX_SLOTS 20480 // sum of per-expert counts padded to 256 <= 16384+16*255
#define MT1 80          // max 256-row m-tiles
#define MT2 160         // max 128-row m-tiles

typedef __attribute__((ext_vector_type(4))) float f32x4;
typedef __attribute__((ext_vector_type(8))) short bf16x8;

__device__ __forceinline__ unsigned short f2bf(float f) {
  union { float f; unsigned u; } v; v.f = f;
  unsigned r = v.u + 0x7FFFu + ((v.u >> 16) & 1u);
  return (unsigned short)(r >> 16);
}

__device__ __forceinline__ void gload16(const void* g, void* l) {
  __builtin_amdgcn_global_load_lds(
      (const __attribute__((address_space(1))) unsigned int*)g,
      (__attribute__((address_space(3))) unsigned int*)l, 16, 0, 0);
}

// ---------------- router ------------------------------------------------------
__global__ void router_kernel(const float* __restrict__ x, const float* __restrict__ Wr,
                              const float* __restrict__ br,
                              int* __restrict__ counts, int* __restrict__ tok_e,
                              int* __restrict__ tok_s, float* __restrict__ tok_w,
                              int* __restrict__ elist) {
  int t = blockIdx.x * blockDim.x + threadIdx.x;
  if (t >= T_TOK) return;
  float acc[EE];
#pragma unroll
  for (int e = 0; e < EE; ++e) acc[e] = br[e];
  const f32x4* x4 = (const f32x4*)(x + (size_t)t * DD);
  for (int d4 = 0; d4 < DD / 4; ++d4) {
    f32x4 xv = x4[d4];
    const float* wr = Wr + (size_t)d4 * 4 * EE;
#pragma unroll
    for (int dd = 0; dd < 4; ++dd)
#pragma unroll
      for (int e = 0; e < EE; ++e) acc[e] += xv[dd] * wr[dd * EE + e];
  }
  int i0 = 0; float v0 = acc[0];
#pragma unroll
  for (int e = 1; e < EE; ++e) if (acc[e] > v0) { v0 = acc[e]; i0 = e; }
  int i1 = -1; float v1 = -3.4e38f;
#pragma unroll
  for (int e = 0; e < EE; ++e) if (e != i0 && acc[e] > v1) { v1 = acc[e]; i1 = e; }
  float p1 = __expf(v1 - v0);
  float w0 = 1.f / (1.f + p1);
  float w1 = p1 * w0;
  int s0 = atomicAdd(&counts[i0], 1);
  int s1 = atomicAdd(&counts[i1], 1);
  tok_e[2 * t] = i0; tok_s[2 * t] = s0; tok_w[2 * t] = w0;
  tok_e[2 * t + 1] = i1; tok_s[2 * t + 1] = s1; tok_w[2 * t + 1] = w1;
  elist[(size_t)i0 * T_TOK + s0] = t;
  elist[(size_t)i1 * T_TOK + s1] = t;
}

// ---------------- scan --------------------------------------------------------
__global__ void scan_kernel(const int* __restrict__ counts, int* __restrict__ off,
                            int* __restrict__ mtb, int* __restrict__ mtb2) {
  if (threadIdx.x == 0 && blockIdx.x == 0) {
    int o = 0, m = 0;
    for (int e = 0; e < EE; ++e) {
      off[e] = o; mtb[e] = m;
      int c = counts[e];
      int mt = (c + 255) / 256;
      o += mt * 256; m += mt;
    }
    off[EE] = o; mtb[EE] = m;
    for (int e = 0; e <= EE; ++e) mtb2[e] = off[e] >> 7;
  }
}

// ---------------- gather ------------------------------------------------------
__global__ void gather_kernel(const float* __restrict__ x, const int* __restrict__ counts,
                              const int* __restrict__ off, const int* __restrict__ elist,
                              unsigned short* __restrict__ Xg) {
  int slot = blockIdx.x;
  if (slot >= off[EE]) return;
  int e = 0;
  while (e < EE - 1 && off[e + 1] <= slot) ++e;
  int s = slot - off[e];
  int tid = threadIdx.x;
  ushort4* dst = (ushort4*)(Xg + (size_t)slot * DD);
  if (s < counts[e]) {
    int t = elist[(size_t)e * T_TOK + s];
    f32x4 v = ((const f32x4*)(x + (size_t)t * DD))[tid];
    ushort4 o;
    o.x = f2bf(v[0]); o.y = f2bf(v[1]); o.z = f2bf(v[2]); o.w = f2bf(v[3]);
    dst[tid] = o;
  } else {
    ushort4 z; z.x = z.y = z.z = z.w = 0;
    dst[tid] = z;
  }
}

// ---------------- transpose+convert fp32[R][C] -> bf16 with optional W13 remap -
__global__ void transpose_conv(const float* __restrict__ src0, unsigned short* __restrict__ dst0,
                               int R, int C, size_t dstEstride, int mode) {
  __shared__ float tile[64][65];
  int e = blockIdx.z;
  const float* src = src0 + (size_t)e * R * C;
  unsigned short* dst = dst0 + (size_t)e * dstEstride;
  int r0 = blockIdx.y * 64, c0 = blockIdx.x * 64;
  int tx = threadIdx.x & 15, ty = threadIdx.x >> 4;
#pragma unroll
  for (int i = 0; i < 4; ++i) {
    int r = i * 16 + ty;
    f32x4 v = *(const f32x4*)(src + (size_t)(r0 + r) * C + c0 + tx * 4);
    tile[r][tx * 4 + 0] = v[0]; tile[r][tx * 4 + 1] = v[1];
    tile[r][tx * 4 + 2] = v[2]; tile[r][tx * 4 + 3] = v[3];
  }
  __syncthreads();
#pragma unroll
  for (int i = 0; i < 4; ++i) {
    int c = i * 16 + ty;
    int cg = c0 + c;
    int rp = (mode == 0) ? cg : ((cg >> 7) * 256 + (cg & 127) + ((mode == 2) ? 128 : 0));
    ushort4 o;
    o.x = f2bf(tile[tx * 4 + 0][c]); o.y = f2bf(tile[tx * 4 + 1][c]);
    o.z = f2bf(tile[tx * 4 + 2][c]); o.w = f2bf(tile[tx * 4 + 3][c]);
    *(ushort4*)(dst + (size_t)rp * R + r0 + tx * 4) = o;
  }
}

// ---------------- GEMM1: 256x256 tile, BK=32, 4 LDS buffers, stage kt+3 -------
// Buffer b (32KB at b*32768): A [256 rows][64B] at +0, B at +16384.
// Row swizzle: LDS[row][slot s] = G[row][kt*32 + (s ^ ((row>>1)&3))*8].
// Per K-tile: 2 phases; vmcnt(8) once per K-tile (drains kt+1's 4 granules,
// issued ~5 phases earlier); never drains to 0 mid-loop.
#define PHASE(MQ, STG, VMW)                                                         \
  do {                                                                              \
    STG;                                                                            \
    if (MQ == 0) {                                                                  \
      _Pragma("unroll") for (int ni = 0; ni < 4; ++ni)                              \
        pb[ni] = *(const bf16x8*)(lds + cb + 16384 +                                \
                                  (wc * 64 + ni * 16 + fr) * 64 + (fkb ^ swz));     \
    }                                                                               \
    _Pragma("unroll") for (int mi = 0; mi < 4; ++mi)                                \
      pa[mi] = *(const bf16x8*)(lds + cb +                                          \
                                (wr * 128 + MQ * 64 + mi * 16 + fr) * 64 + (fkb ^ swz)); \
    VMW;                                                                            \
    __builtin_amdgcn_s_barrier();                                                   \
    asm volatile("s_waitcnt lgkmcnt(0)" ::: "memory");                              \
    __builtin_amdgcn_sched_barrier(0);                                              \
    __builtin_amdgcn_s_setprio(1);                                                  \
    _Pragma("unroll") for (int mi = 0; mi < 4; ++mi)                                \
      _Pragma("unroll") for (int ni = 0; ni < 4; ++ni)                              \
        acc[MQ * 4 + mi][ni] = __builtin_amdgcn_mfma_f32_16x16x32_bf16(             \
            pa[mi], pb[ni], acc[MQ * 4 + mi][ni], 0, 0, 0);                         \
    __builtin_amdgcn_s_setprio(0);                                                  \
    __builtin_amdgcn_s_barrier();                                                   \
  } while (0)

__global__ __launch_bounds__(512, 2) void gemm1_kernel(
    const unsigned short* __restrict__ Xg, const unsigned short* __restrict__ W13t,
    const int* __restrict__ off, const int* __restrict__ mtb,
    unsigned short* __restrict__ H) {
  __shared__ __align__(16) char lds[131072];
  int ty = blockIdx.y;
  if (ty >= mtb[EE]) return;
  int e = 0;
  while (e < EE - 1 && mtb[e + 1] <= ty) ++e;
  int m0 = off[e] + (ty - mtb[e]) * 256;
  int n0s = blockIdx.x * 256;
  int hcol0 = blockIdx.x * 128;
  const unsigned short* Ag = Xg + (size_t)m0 * DD;
  const unsigned short* Bg = W13t + ((size_t)e * (2 * FF) + n0s) * DD;

  int tid = threadIdx.x, lane = tid & 63, wid = tid >> 6;
  int wr = wid >> 2, wc = wid & 3;
  int fr = lane & 15, fkb = (lane >> 4) * 16;  // k-byte within 64B row
  int swz = ((fr >> 1) & 3) << 4;
  int ce8 = ((tid & 3) ^ ((tid >> 3) & 3)) * 8;  // inverse-swizzled source chunk

  auto stageA = [&](int buf, int kt2) {
    int dst = buf << 15;
#pragma unroll
    for (int L = 0; L < 2; ++L) {
      int row = L * 128 + (tid >> 2);
      gload16(Ag + (size_t)row * DD + kt2 * 32 + ce8, lds + dst + L * 8192 + tid * 16);
    }
  };
  auto stageB = [&](int buf, int kt2) {
    int dst = (buf << 15) + 16384;
#pragma unroll
    for (int L = 0; L < 2; ++L) {
      int row = L * 128 + (tid >> 2);
      gload16(Bg + (size_t)row * DD + kt2 * 32 + ce8, lds + dst + L * 8192 + tid * 16);
    }
  };

  f32x4 acc[8][4] = {};
  bf16x8 pa[4], pb[4];

  // prologue: stage K-tiles 0,1,2 (12 loads); wait kt0 landed (8 remain)
  asm volatile("s_waitcnt vmcnt(0)" ::: "memory");
  stageA(0, 0); stageB(0, 0);
  stageA(1, 1); stageB(1, 1);
  stageA(2, 2); stageB(2, 2);
  asm volatile("s_waitcnt vmcnt(8)" ::: "memory");
  __builtin_amdgcn_s_barrier();

  for (int kt = 0; kt < 29; ++kt) {
    int cb = (kt & 3) << 15;
    int nb = (kt + 3) & 3;
    PHASE(0, stageA(nb, kt + 3), ((void)0));
    PHASE(1, stageB(nb, kt + 3), asm volatile("s_waitcnt vmcnt(8)" ::: "memory"));
  }
  {
    int cb = (29 & 3) << 15;
    PHASE(0, ((void)0), ((void)0));
    PHASE(1, ((void)0), asm volatile("s_waitcnt vmcnt(4)" ::: "memory"));
  }
  {
    int cb = (30 & 3) << 15;
    PHASE(0, ((void)0), ((void)0));
    PHASE(1, ((void)0), asm volatile("s_waitcnt vmcnt(0)" ::: "memory"));
  }
  {
    int cb = (31 & 3) << 15;
    PHASE(0, ((void)0), ((void)0));
    PHASE(1, ((void)0), ((void)0));
  }

  // epilogue: SwiGLU combine via LDS, then coalesced bf16 store
  float* L3 = (float*)lds;                               // [128][132] f32
  unsigned short* HO = (unsigned short*)(lds + 69632);   // [128][128] bf16
  int frow = (lane >> 4) * 4;
#pragma unroll 1
  for (int h = 0; h < 2; ++h) {
    __syncthreads();
    if (wr == h && wc >= 2) {
#pragma unroll
      for (int mi = 0; mi < 8; ++mi)
#pragma unroll
        for (int ni = 0; ni < 4; ++ni)
#pragma unroll
          for (int i = 0; i < 4; ++i)
            L3[(mi * 16 + frow + i) * 132 + (wc - 2) * 64 + ni * 16 + fr] = acc[mi][ni][i];
    }
    __syncthreads();
    if (wr == h && wc < 2) {
#pragma unroll
      for (int mi = 0; mi < 8; ++mi)
#pragma unroll
        for (int ni = 0; ni < 4; ++ni)
#pragma unroll
          for (int i = 0; i < 4; ++i) {
            float c1 = acc[mi][ni][i];
            float c3 = L3[(mi * 16 + frow + i) * 132 + wc * 64 + ni * 16 + fr];
            float hv = c1 / (1.f + __expf(-c1)) * c3;
            HO[(mi * 16 + frow + i) * 128 + wc * 64 + ni * 16 + fr] = f2bf(hv);
          }
    }
    __syncthreads();
#pragma unroll
    for (int s = 0; s < 4; ++s) {
      int flat = s * 8192 + tid * 16;
      int rr = flat >> 8, cb2 = flat & 255;
      *(bf16x8*)(H + (size_t)(m0 + h * 128 + rr) * FF + hcol0 + (cb2 >> 1)) =
          *(const bf16x8*)((const char*)HO + flat);
    }
    __syncthreads();
  }
}

// ---------------- GEMM2: Y = H @ W2t (128x128, unchanged structure) ------------
__global__ __launch_bounds__(256, 2) void gemm2_kernel(
    const unsigned short* __restrict__ H, const unsigned short* __restrict__ W2t,
    const int* __restrict__ off, const int* __restrict__ mtb2, float* __restrict__ Y) {
  __shared__ __align__(16) unsigned short As[128][32];
  __shared__ __align__(16) unsigned short Bs[128][32];
  int ty = blockIdx.y;
  if (ty >= mtb2[EE]) return;
  int e = 0;
  while (e < EE - 1 && mtb2[e + 1] <= ty) ++e;
  int m0 = off[e] + (ty - mtb2[e]) * 128;
  int n0 = blockIdx.x * 128;
  const unsigned short* A = H + (size_t)m0 * FF;
  const unsigned short* B = W2t + ((size_t)e * DD + n0) * FF;
  int tid = threadIdx.x, lane = tid & 63, wid = tid >> 6;
  int wm = wid >> 1, wn = wid & 1;
  f32x4 acc[4][4] = {};
  int fr = lane & 15, fk = (lane >> 4) * 8;
  for (int k0 = 0; k0 < FF; k0 += 32) {
#pragma unroll
    for (int r = 0; r < 2; ++r) {
      int c = r * 256 + tid;
      int row = c >> 2, ch = c & 3;
      gload16(A + (size_t)row * FF + k0 + ch * 8, (char*)As + c * 16);
      gload16(B + (size_t)row * FF + k0 + ch * 8, (char*)Bs + c * 16);
    }
    __syncthreads();
    bf16x8 a[4], b[4];
#pragma unroll
    for (int mi = 0; mi < 4; ++mi) a[mi] = *(const bf16x8*)&As[wm * 64 + mi * 16 + fr][fk];
#pragma unroll
    for (int ni = 0; ni < 4; ++ni) b[ni] = *(const bf16x8*)&Bs[wn * 64 + ni * 16 + fr][fk];
#pragma unroll
    for (int mi = 0; mi < 4; ++mi)
#pragma unroll
      for (int ni = 0; ni < 4; ++ni)
        acc[mi][ni] = __builtin_amdgcn_mfma_f32_16x16x32_bf16(a[mi], b[ni], acc[mi][ni], 0, 0, 0);
    __syncthreads();
  }
#pragma unroll
  for (int mi = 0; mi < 4; ++mi)
#pragma unroll
    for (int ni = 0; ni < 4; ++ni)
#pragma unroll
      for (int i = 0; i < 4; ++i) {
        int row = m0 + wm * 64 + mi * 16 + (lane >> 4) * 4 + i;
        int col = n0 + wn * 64 + ni * 16 + (lane & 15);
        Y[(size_t)row * DD + col] = acc[mi][ni][i];
      }
}

// ---------------- LayerNorm + weighted combine ---------------------------------
__global__ void ln_combine_kernel(const float* __restrict__ Y, const int* __restrict__ tok_e,
                                  const int* __restrict__ tok_s, const float* __restrict__ tok_w,
                                  const int* __restrict__ off, const float* __restrict__ gamma,
                                  const float* __restrict__ beta, float* __restrict__ out) {
  int t = blockIdx.x, tid = threadIdx.x;
  __shared__ float red[8];
  f32x4 o = {0.f, 0.f, 0.f, 0.f};
  for (int k = 0; k < 2; ++k) {
    int e = tok_e[2 * t + k], s = tok_s[2 * t + k];
    float w = tok_w[2 * t + k];
    int slot = off[e] + s;
    f32x4 v = ((const f32x4*)(Y + (size_t)slot * DD))[tid];
    float sum = v[0] + v[1] + v[2] + v[3];
    float sq = v[0] * v[0] + v[1] * v[1] + v[2] * v[2] + v[3] * v[3];
    for (int d = 32; d > 0; d >>= 1) {
      sum += __shfl_down(sum, d);
      sq += __shfl_down(sq, d);
    }
    int wv = tid >> 6, lane = tid & 63;
    if (lane == 0) { red[wv * 2] = sum; red[wv * 2 + 1] = sq; }
    __syncthreads();
    float S1 = red[0] + red[2] + red[4] + red[6];
    float S2 = red[1] + red[3] + red[5] + red[7];
    __syncthreads();
    float mu = S1 * (1.f / (float)DD);
    float var = S2 * (1.f / (float)DD) - mu * mu;
    float rs = rsqrtf(var + 1e-5f);
    f32x4 g = ((const f32x4*)(gamma + (size_t)e * DD))[tid];
    f32x4 b = ((const f32x4*)(beta + (size_t)e * DD))[tid];
#pragma unroll
    for (int j = 0; j < 4; ++j) o[j] += w * ((v[j] - mu) * rs * g[j] + b[j]);
  }
  ((f32x4*)out)[(size_t)t * (DD / 4) + tid] = o;
}

// ---------------- launch -------------------------------------------------------
extern "C" void kernel_launch(void* const* d_in, const int* in_sizes, int n_in,
                              void* d_out, int out_size, void* d_ws, size_t ws_size,
                              hipStream_t stream) {
  const float* x = (const float*)d_in[0];
  const float* Wr = (const float*)d_in[1];
  const float* br = (const float*)d_in[2];
  const float* W1 = (const float*)d_in[3];
  const float* W3 = (const float*)d_in[4];
  const float* W2 = (const float*)d_in[5];
  const float* gamma = (const float*)d_in[6];
  const float* beta = (const float*)d_in[7];
  float* out = (float*)d_out;

  char* w = (char*)d_ws;
  size_t o = 0;
  auto alloc = [&](size_t bytes) {
    void* p = w + o;
    o += (bytes + 255) & ~(size_t)255;
    return p;
  };
  int* counts = (int*)alloc(EE * 4);
  int* off = (int*)alloc((EE + 1) * 4);
  int* mtb = (int*)alloc((EE + 1) * 4);
  int* mtb2 = (int*)alloc((EE + 1) * 4);
  int* tok_e = (int*)alloc(2 * T_TOK * 4);
  int* tok_s = (int*)alloc(2 * T_TOK * 4);
  float* tok_w = (float*)alloc(2 * T_TOK * 4);
  int* elist = (int*)alloc((size_t)EE * T_TOK * 4);
  unsigned short* Xg = (unsigned short*)alloc((size_t)MAX_SLOTS * DD * 2);
  unsigned short* W13t = (unsigned short*)alloc((size_t)EE * 2 * FF * DD * 2);
  unsigned short* W2t = (unsigned short*)alloc((size_t)EE * DD * FF * 2);
  unsigned short* Hb = (unsigned short*)alloc((size_t)MAX_SLOTS * FF * 2);
  float* Y = (float*)alloc((size_t)MAX_SLOTS * DD * 4);

  hipMemsetAsync(counts, 0, EE * sizeof(int), stream);
  router_kernel<<<T_TOK / 256, 256, 0, stream>>>(x, Wr, br, counts, tok_e, tok_s, tok_w, elist);
  scan_kernel<<<1, 64, 0, stream>>>(counts, off, mtb, mtb2);
  gather_kernel<<<MAX_SLOTS, 256, 0, stream>>>(x, counts, off, elist, Xg);
  transpose_conv<<<dim3(FF / 64, DD / 64, EE), 256, 0, stream>>>(W1, W13t, DD, FF, (size_t)2 * FF * DD, 1);
  transpose_conv<<<dim3(FF / 64, DD / 64, EE), 256, 0, stream>>>(W3, W13t, DD, FF, (size_t)2 * FF * DD, 2);
  transpose_conv<<<dim3(DD / 64, FF / 64, EE), 256, 0, stream>>>(W2, W2t, FF, DD, (size_t)FF * DD, 0);
  gemm1_kernel<<<dim3(2 * FF / 256, MT1), 512, 0, stream>>>(Xg, W13t, off, mtb, Hb);
  gemm2_kernel<<<dim3(DD / 128, MT2), 256, 0, stream>>>(Hb, W2t, off, mtb2, Y);
  ln_combine_kernel<<<T_TOK, 256, 0, stream>>>(Y, tok_e, tok_s, tok_w, off, gamma, beta, out);
}